// Round 8
// baseline (330.474 us; speedup 1.0000x reference)
//
#include <hip/hip_runtime.h>
#include <cstddef>

static constexpr int CB = 64;    // batch
static constexpr int CN = 512;   // nodes
static constexpr int CD = 256;   // node model dim
static constexpr int CE = 128;   // edge model dim
static constexpr int CIT = 20;   // sinkhorn iterations

typedef _Float16 half_t;
typedef __attribute__((ext_vector_type(8))) _Float16 v8h;
typedef __attribute__((ext_vector_type(4))) _Float16 v4h;
typedef __attribute__((ext_vector_type(4))) float v4f;

// ---------------------------------------------------------------------------
// LLC-coherent ops. NO fences / cache-maintenance (R1: release/acquire =>
// buffer_wbl2/inv storms). Ordering primitive (R6/R7-validated): sc0sc1
// stores + per-thread s_waitcnt vmcnt(0) + block barrier => payload at LLC
// BEFORE the subsequent marker store; peers observing the marker read the
// payload with one-shot loads.
// Protocol ledger (sinkhorn period ~5.5-6 us/iter in ALL): R0 scalar-atomic
// poll 160.7 | R2 16B payload-poll 158.4 | R3 +L2 channel 173 | R4 +XCD
// remap 190 | R7 marker-gated 197(mega) FETCH 84->72. Conclusion: cost =
// ~3 sequential cross-die LLC RTs (~1.2 us each) + skew, NOT poll traffic.
// Exchange protocol FROZEN at marker-gated (no preclear, graph-safe).
// ---------------------------------------------------------------------------
__device__ __forceinline__ void llc_store4(v4f* p, v4f v) {
  asm volatile("global_store_dwordx4 %0, %1, off sc0 sc1"
               :: "v"(p), "v"(v) : "memory");
}
__device__ __forceinline__ void llc_storef(float* p, float v) {
  asm volatile("global_store_dword %0, %1, off sc0 sc1"
               :: "v"(p), "v"(v) : "memory");
}
__device__ __forceinline__ void llc_load3x4(const v4f* p0, const v4f* p1,
                                            const v4f* p2,
                                            v4f& a, v4f& b, v4f& c) {
  asm volatile("global_load_dwordx4 %0, %3, off sc0 sc1\n\t"
               "global_load_dwordx4 %1, %4, off sc0 sc1\n\t"
               "global_load_dwordx4 %2, %5, off sc0 sc1\n\t"
               "s_waitcnt vmcnt(0)"
               : "=&v"(a), "=&v"(b), "=&v"(c)
               : "v"(p0), "v"(p1), "v"(p2)
               : "memory");
}
__device__ __forceinline__ float llc_loadf(const float* p) {
  float v;
  asm volatile("global_load_dword %0, %1, off sc0 sc1\n\t"
               "s_waitcnt vmcnt(0)"
               : "=v"(v) : "v"(p) : "memory");
  return v;
}
// Narrow marker poll: lanes 0-2 of the calling wave each watch one remote
// slab's marker (12 B/round/wave, hot line); wave exits when all 3 passed.
__device__ __forceinline__ void wait_marker(const float* mk, int rsl, int ln,
                                            float target) {
  while (true) {
    float f = 1e30f;
    if (ln < 3) f = llc_loadf(&mk[rsl]);
    if (__all(f > target)) break;
    __builtin_amdgcn_s_sleep(1);
  }
}

// ---------------------------------------------------------------------------
// k0: block 0 = mask dtype detect; block 1 = clear the 256 markers to -1
// (1 KB); 2..9 = W_a -> fp16 B-fragments (w_aff folded); 10..17 = W_b.
// flag: 0=int32, 1=uint8(bool), 2=float32, 3=int64
// ---------------------------------------------------------------------------
__global__ __launch_bounds__(512) void k0_init(
    const void* __restrict__ mask, int* __restrict__ flag,
    const float* __restrict__ W_a, const float* __restrict__ W_b,
    const float* __restrict__ w_aff,
    half_t* __restrict__ WaF, half_t* __restrict__ WbF,
    float4* __restrict__ markers4) {
  const int tid = threadIdx.x;
  const int blk = blockIdx.x;
  if (blk == 1) {
    if (tid < CB * 4 / 4)   // 64 float4 = 256 marker floats
      markers4[tid] = make_float4(-1.0f, -1.0f, -1.0f, -1.0f);
    return;
  }
  if (blk >= 2) {
    const bool is_a = (blk < 10);
    const float* W = is_a ? W_a : W_b;
    half_t* WF = is_a ? WaF : WbF;
    const int e = (blk - (is_a ? 2 : 10)) * 512 + tid;   // 0..4095
    const int fB = e >> 6, lane = e & 63;
    const int nn = fB >> 3, kf = fB & 7;
    const int col = nn * 16 + (lane & 15);
    const int q = lane >> 4;
    const float scale = is_a ? w_aff[col] : 1.0f;
    v8h hv;
#pragma unroll
    for (int j = 0; j < 8; ++j) {
      const int k = kf * 32 + q * 8 + j;
      hv[j] = (half_t)(W[(size_t)k * CE + col] * scale);
    }
    *(v8h*)&WF[(size_t)e * 8] = hv;
    return;
  }
  // blk == 0: mask dtype detection over first 32768 bytes
  __shared__ int cnt[5];
  if (tid < 5) cnt[tid] = 0;
  __syncthreads();
  const unsigned char* p = (const unsigned char*)mask;
  int l0 = 0, l1 = 0, l2 = 0, l3 = 0, l4 = 0;
  const int base = tid * 64;
  for (int k = 0; k < 64; ++k) {
    const int off = base + k;
    if (p[off]) {
      const int m4 = off & 3;
      if (m4 == 1) l1++;
      else if (m4 == 2) l2++;
      else if (m4 == 3) l3++;
      else if ((off & 7) == 4) l4++;
      else l0++;
    }
  }
  if (l0) atomicAdd(&cnt[0], 1);
  if (l1) atomicAdd(&cnt[1], 1);
  if (l2) atomicAdd(&cnt[2], 1);
  if (l3) atomicAdd(&cnt[3], 1);
  if (l4) atomicAdd(&cnt[4], 1);
  __syncthreads();
  if (tid == 0) {
    int f;
    if (cnt[1]) f = 1;
    else if (cnt[2] || cnt[3]) f = 2;
    else if (cnt[4]) f = 0;
    else if (cnt[0]) f = 3;
    else f = 1;
    *flag = f;
  }
}

// ---------------------------------------------------------------------------
// mega: prep + sinkhorn in ONE dispatch. Block = (b, slab).
// R8 reorder: B-prep FIRST (publish + marker as early as possible), THEN
// A-prep (block-local; runs during peers' B-prep skew + marker RT), then
// wait markers -> E-GEMM -> sinkhorn (marker-gated) -> vectorized finalize.
// Grid 256 = 1 block/CU => co-residency.
// ---------------------------------------------------------------------------
__global__ __launch_bounds__(512, 2) void mega(
    const float* __restrict__ out_emb, const float* __restrict__ pos,
    const float* __restrict__ in_emb, const float* __restrict__ pad,
    const void* __restrict__ maskp, const int* __restrict__ flagp,
    const half_t* __restrict__ WaF, const half_t* __restrict__ WbF,
    half_t* __restrict__ Bm_h,
    const float* __restrict__ baff, float* __restrict__ P,
    float* __restrict__ partInit, float* __restrict__ partIter,
    float* __restrict__ markers) {
  // smem2: A/B bounce [128][136] halfs (34816 B), later aliased as comb2
  __shared__ __align__(16) char smem2[34816];
  __shared__ __align__(16) float2 w12[512];    // {0.5*v*csinv, v} (finalize)
  __shared__ __align__(16) float QsL[512];     // per-col publish staging
  __shared__ __align__(16) v4f csinv4[128];    // 1/colsum, 4 cols per slot
  __shared__ __align__(16) half_t wAll[1056];  // w1 @0, w2 @544 (+16 banks)
  half_t* bounce = (half_t*)smem2;
  float (*comb2)[512][2] = (float (*)[512][2])smem2;   // 32 KB <= 34816

  const int tid = threadIdx.x;
  const int wv = tid >> 6, ln = tid & 63;
  const int q = ln >> 4, l = ln & 15;
  const int b = blockIdx.x & 63;
  const int slab = blockIdx.x >> 6;
  const int i0 = slab * 128;
  const float bbs = *baff - 2.7725887f;   // fold 2^-4 scale into exp

  int rs3[3];   // the 3 remote slabs (static-indexed only)
  {
    int k = 0;
#pragma unroll
    for (int sl = 0; sl < 4; ++sl)
      if (sl != slab) rs3[k++] = sl;
  }
  const int rsl = (ln < 3) ? (ln + (ln >= slab ? 1 : 0)) : 0;
  float* mk = &markers[(size_t)b * 4];

  // ================= P1: B-prep + publish (FIRST — critical path) ========
  {
    const int flag = *flagp;
    const int row = wv * 16 + l;
    const int grow = b * CN + i0 + row;
    bool m;
    if (flag == 1)      m = ((const unsigned char*)maskp)[grow] != 0;
    else if (flag == 2) m = ((const float*)maskp)[grow] != 0.0f;
    else if (flag == 3) m = ((const long long*)maskp)[grow] != 0;
    else                m = ((const int*)maskp)[grow] != 0;
    const size_t xr = (size_t)grow * CD;
    v8h xf[8];
#pragma unroll
    for (int kf = 0; kf < 8; ++kf) {
      const int c = kf * 32 + q * 8;
      float4 a0, a1;
      if (m) {
        a0 = *(const float4*)&pad[c];
        a1 = *(const float4*)&pad[c + 4];
      } else {
        a0 = *(const float4*)&in_emb[xr + c];
        a1 = *(const float4*)&in_emb[xr + c + 4];
      }
      v8h h;
      h[0] = (half_t)a0.x; h[1] = (half_t)a0.y;
      h[2] = (half_t)a0.z; h[3] = (half_t)a0.w;
      h[4] = (half_t)a1.x; h[5] = (half_t)a1.y;
      h[6] = (half_t)a1.z; h[7] = (half_t)a1.w;
      xf[kf] = h;
    }
    v4f acc[8] = {};
#pragma unroll
    for (int nn = 0; nn < 8; ++nn)
#pragma unroll
      for (int kf = 0; kf < 8; ++kf) {
        const v8h bw = *(const v8h*)&WbF[(size_t)((nn * 8 + kf) * 64 + ln) * 8];
        acc[nn] = __builtin_amdgcn_mfma_f32_16x16x32_f16(xf[kf], bw, acc[nn], 0, 0, 0);
      }
#pragma unroll
    for (int nn = 0; nn < 8; ++nn)
#pragma unroll
      for (int g = 0; g < 4; ++g)
        bounce[(size_t)(wv * 16 + q * 4 + g) * 136 + nn * 16 + l] = (half_t)acc[nn][g];
  }
  __syncthreads();
  // coalesced sc0sc1 store of the B-slab to Bm (rows i0..i0+127)
  {
    const int row = tid >> 2, qt = tid & 3;
    half_t* dst = &Bm_h[((size_t)b * CN + i0 + row) * CE + qt * 32];
    const half_t* src = &bounce[(size_t)row * 136 + qt * 32];
#pragma unroll
    for (int j = 0; j < 4; ++j)
      llc_store4((v4f*)&dst[j * 8], *(const v4f*)&src[j * 8]);
    asm volatile("s_waitcnt vmcnt(0)" ::: "memory");
  }
  __syncthreads();   // all waves drained => B-slab fully at LLC
  if (tid == 0) llc_storef(&mk[slab], 1.0f);

  // ================= P2: A-prep (block-local, hides peer skew) ============
  v8h af[4];
  {
    const int row = wv * 16 + l;                    // local row 0..127
    const size_t xr = ((size_t)b * CN + i0 + row) * CD;
    const size_t pr = (size_t)(i0 + row) * CD;
    v8h xf[8];
#pragma unroll
    for (int kf = 0; kf < 8; ++kf) {
      const int c = kf * 32 + q * 8;
      float4 a0 = *(const float4*)&out_emb[xr + c];
      float4 a1 = *(const float4*)&out_emb[xr + c + 4];
      const float4 p0 = *(const float4*)&pos[pr + c];
      const float4 p1 = *(const float4*)&pos[pr + c + 4];
      a0.x += p0.x; a0.y += p0.y; a0.z += p0.z; a0.w += p0.w;
      a1.x += p1.x; a1.y += p1.y; a1.z += p1.z; a1.w += p1.w;
      v8h h;
      h[0] = (half_t)a0.x; h[1] = (half_t)a0.y;
      h[2] = (half_t)a0.z; h[3] = (half_t)a0.w;
      h[4] = (half_t)a1.x; h[5] = (half_t)a1.y;
      h[6] = (half_t)a1.z; h[7] = (half_t)a1.w;
      xf[kf] = h;
    }
    v4f acc[8] = {};
#pragma unroll
    for (int nn = 0; nn < 8; ++nn)
#pragma unroll
      for (int kf = 0; kf < 8; ++kf) {
        const v8h bw = *(const v8h*)&WaF[(size_t)((nn * 8 + kf) * 64 + ln) * 8];
        acc[nn] = __builtin_amdgcn_mfma_f32_16x16x32_f16(xf[kf], bw, acc[nn], 0, 0, 0);
      }
    __syncthreads();   // B-publish reads of bounce complete (barrier above)
#pragma unroll
    for (int nn = 0; nn < 8; ++nn)
#pragma unroll
      for (int g = 0; g < 4; ++g)
        bounce[(size_t)(wv * 16 + q * 4 + g) * 136 + nn * 16 + l] = (half_t)acc[nn][g];
  }
  __syncthreads();
#pragma unroll
  for (int ki = 0; ki < 4; ++ki)
    af[ki] = *(const v8h*)&bounce[(size_t)(wv * 16 + l) * 136 + ki * 32 + q * 8];

  // ================= P3: wait peers (markers), then E-GEMM =================
  wait_marker(mk, rsl, ln, 0.5f);   // per-wave, 3 scalar loads/round

  v4h eh[32];    // E[row = wv*16 + q*4+g][col = ct*16 + l]
  v4h ehT[32];   // E[row = wv*16 + l][col = ct*16 + q*4+g]
  {
    const half_t* Bbase = &Bm_h[(size_t)b * CN * CE];
#pragma unroll
    for (int ct = 0; ct < 32; ++ct) {
      v8h bf[4];
      const half_t* Brow = &Bbase[(size_t)(ct * 16 + l) * CE];
#pragma unroll
      for (int ki = 0; ki < 4; ++ki)
        bf[ki] = *(const v8h*)&Brow[ki * 32 + q * 8];
      v4f acc = {}, accT = {};
#pragma unroll
      for (int ki = 0; ki < 4; ++ki) {
        acc  = __builtin_amdgcn_mfma_f32_16x16x32_f16(af[ki], bf[ki], acc,  0, 0, 0);
        accT = __builtin_amdgcn_mfma_f32_16x16x32_f16(bf[ki], af[ki], accT, 0, 0, 0);
      }
#pragma unroll
      for (int g = 0; g < 4; ++g) {
        eh[ct][g]  = (half_t)__expf(acc[g]  + bbs);
        ehT[ct][g] = (half_t)__expf(accT[g] + bbs);
      }
    }
  }
  __syncthreads();   // bounce -> comb2 alias switch

  // ================= P4: sinkhorn =================
  v4h ones;
  ones[0] = (half_t)1.0f; ones[1] = (half_t)1.0f;
  ones[2] = (half_t)1.0f; ones[3] = (half_t)1.0f;
  v4f rowacc0 = {}, rowacc1 = {};
#pragma unroll
  for (int ct = 0; ct < 32; ct += 2) {
    const v4f c0 = __builtin_amdgcn_mfma_f32_16x16x16f16(ones, eh[ct], (v4f){}, 0, 0, 0);
    const v4f c1 = __builtin_amdgcn_mfma_f32_16x16x16f16(ones, eh[ct + 1], (v4f){}, 0, 0, 0);
    if (ln < 16) {
      comb2[wv][ct * 16 + ln][0] = c0[0];
      comb2[wv][(ct + 1) * 16 + ln][0] = c1[0];
    }
    rowacc0 = __builtin_amdgcn_mfma_f32_16x16x16f16(ones, ehT[ct],     rowacc0, 0, 0, 0);
    rowacc1 = __builtin_amdgcn_mfma_f32_16x16x16f16(ones, ehT[ct + 1], rowacc1, 0, 0, 0);
  }
  const float rowtot = rowacc0[0] + rowacc1[0];
  float rv[4];
#pragma unroll
  for (int g = 0; g < 4; ++g)
    rv[g] = 1.0f / __shfl(rowtot, q * 4 + g);
  __syncthreads();

  // ---- init exchange: marker-gated (marker 2.0) ----
  {
    float S = 0.0f;
#pragma unroll
    for (int w = 0; w < 8; ++w) S += comb2[w][tid][0];
    QsL[tid] = S;
  }
  __syncthreads();
  v4f s4 = {};
  if (tid < 128) {
    s4 = *(const v4f*)&QsL[tid * 4];
    v4f* pi4 = (v4f*)partInit + (size_t)b * 4 * 128;
    llc_store4(&pi4[slab * 128 + tid], s4);
    asm volatile("s_waitcnt vmcnt(0)" ::: "memory");
  }
  __syncthreads();   // payload fully at LLC before marker
  if (tid < 128) {
    if (tid == 0) llc_storef(&mk[slab], 2.0f);
    wait_marker(mk, rsl, ln, 1.5f);
    v4f* pi4 = (v4f*)partInit + (size_t)b * 4 * 128;
    v4f r0, r1, r2;
    llc_load3x4(&pi4[rs3[0] * 128 + tid], &pi4[rs3[1] * 128 + tid],
                &pi4[rs3[2] * 128 + tid], r0, r1, r2);
    const v4f T = s4 + r0 + r1 + r2;
    v4f ci;
    v4h w1v, w2v;
#pragma unroll
    for (int j = 0; j < 4; ++j) {
      ci[j] = 1.0f / T[j];
      w1v[j] = (half_t)(0.5f * ci[j]);
      w2v[j] = (half_t)1.0f;
    }
    csinv4[tid] = ci;
    *(v4h*)&wAll[tid * 4] = w1v;
    *(v4h*)&wAll[544 + tid * 4] = w2v;
  }
  __syncthreads();
  const float ci0 = ((const float*)csinv4)[tid];

  // ---- 20 iterations, marker-gated exchange (marker 3.0+t) ----
  const half_t* wbase = (l == 1) ? (wAll + 544) : wAll;   // row0=w1, row1=w2
  float u_[4], uri[4];
  for (int t = 0; t < CIT; ++t) {
    __syncthreads();
    v4f Pe = {}, Po = {};
#pragma unroll
    for (int ct = 0; ct < 32; ct += 2) {
      const v4h wf0 = *(const v4h*)&wbase[ct * 16 + q * 4];
      const v4h wf1 = *(const v4h*)&wbase[(ct + 1) * 16 + q * 4];
      Pe = __builtin_amdgcn_mfma_f32_16x16x16f16(wf0, ehT[ct],     Pe, 0, 0, 0);
      Po = __builtin_amdgcn_mfma_f32_16x16x16f16(wf1, ehT[ct + 1], Po, 0, 0, 0);
    }
    const float Prow1 = Pe[0] + Po[0];
    const float Prow2 = Pe[1] + Po[1];
    v4h u_h, uri_h;
#pragma unroll
    for (int g = 0; g < 4; ++g) {
      const float p1 = __shfl(Prow1, q * 4 + g);
      const float p2 = __shfl(Prow2, q * 4 + g);
      u_[g] = 1.0f / (p1 + 0.5f * rv[g] * p2);
      uri[g] = u_[g] * rv[g];
      u_h[g] = (half_t)u_[g];
      uri_h[g] = (half_t)uri[g];
    }
    const v4h a2 = (l == 1) ? uri_h : u_h;
#pragma unroll
    for (int ct = 0; ct < 32; ++ct) {
      const v4f s = __builtin_amdgcn_mfma_f32_16x16x16f16(a2, eh[ct], (v4f){}, 0, 0, 0);
      if (ln < 16)
        *(float2*)&comb2[wv][ct * 16 + ln][0] = make_float2(s[0], s[1]);
    }
    __syncthreads();
    {
      float S1 = 0.0f, S2 = 0.0f;
#pragma unroll
      for (int w = 0; w < 8; ++w) {
        const float2 c2v = *(const float2*)&comb2[w][tid][0];
        S1 += c2v.x;
        S2 += c2v.y;
      }
      QsL[tid] = 0.5f * fmaf(ci0, S1, S2);
    }
    __syncthreads();
    v4f Q4 = {};
    if (tid < 128) {
      Q4 = *(const v4f*)&QsL[tid * 4];
      v4f* pr4 = (v4f*)partIter + (((size_t)t * 64 + b) * 4) * 128;
      llc_store4(&pr4[slab * 128 + tid], Q4);
      asm volatile("s_waitcnt vmcnt(0)" ::: "memory");
    }
    __syncthreads();   // payload fully at LLC before marker
    if (tid < 128) {
      if (tid == 0) llc_storef(&mk[slab], 3.0f + (float)t);
      wait_marker(mk, rsl, ln, 2.5f + (float)t);
      v4f* pr4 = (v4f*)partIter + (((size_t)t * 64 + b) * 4) * 128;
      v4f r0, r1, r2;
      llc_load3x4(&pr4[rs3[0] * 128 + tid], &pr4[rs3[1] * 128 + tid],
                  &pr4[rs3[2] * 128 + tid], r0, r1, r2);
      const v4f tot = Q4 + r0 + r1 + r2;
      const v4f ci = csinv4[tid];
      v4h w1v, w2v;
#pragma unroll
      for (int j = 0; j < 4; ++j) {
        const float vv = 1.0f / tot[j];
        w1v[j] = (half_t)(0.5f * vv * ci[j]);
        w2v[j] = (half_t)vv;
        if (t == CIT - 1)
          w12[tid * 4 + j] = make_float2(0.5f * vv * ci[j], vv);
      }
      *(v4h*)&wAll[tid * 4] = w1v;
      *(v4h*)&wAll[544 + tid * 4] = w2v;
    }
  }

  // ---- finalize: P = E * u_i * v_j * (0.5*csinv_j + 0.5*rinv_i) ----
  // R8: g-outer (row-major page locality) + shfl_xor column pairing ->
  // float2 stores on even lanes (half the store instructions).
  __syncthreads();
#pragma unroll
  for (int g = 0; g < 4; ++g) {
    float* Pg = &P[((size_t)b * CN + i0 + wv * 16 + q * 4 + g) * CN];
#pragma unroll
    for (int ct = 0; ct < 32; ++ct) {
      const float2 w = w12[ct * 16 + l];
      const float val = (float)eh[ct][g] * fmaf(u_[g], w.x, uri[g] * (0.5f * w.y));
      const float par = __shfl_xor(val, 1);
      if ((l & 1) == 0)
        *(float2*)&Pg[ct * 16 + l] = make_float2(val, par);
    }
  }
}

// ---------------------------------------------------------------------------
extern "C" void kernel_launch(void* const* d_in, const int* in_sizes, int n_in,
                              void* d_out, int out_size, void* d_ws, size_t ws_size,
                              hipStream_t stream) {
  const float* in_emb  = (const float*)d_in[0];
  const void*  mask    = d_in[1];
  const float* out_emb = (const float*)d_in[2];
  const float* pad     = (const float*)d_in[3];
  const float* pos     = (const float*)d_in[4];
  const float* W_a     = (const float*)d_in[5];
  const float* W_b     = (const float*)d_in[6];
  const float* w_aff   = (const float*)d_in[7];
  const float* b_aff   = (const float*)d_in[8];
  float* P = (float*)d_out;

  char* ws = (char*)d_ws;
  const size_t MB = 1024 * 1024;
  const size_t KB = 1024;
  half_t* Bm_h = (half_t*)ws;                              // 8 MB
  int*    flag = (int*)(ws + 8 * MB);                      // 4 B
  half_t* WaF  = (half_t*)(ws + 8 * MB + 16 * KB);         // 64 KB
  half_t* WbF  = (half_t*)(ws + 8 * MB + 80 * KB);         // 64 KB
  float* partInit = (float*)(ws + 9 * MB);                 // 512 KB (no preclear)
  float* partIter = (float*)(ws + 9 * MB + 512 * KB);      // 10 MB (no preclear)
  float* markers  = (float*)(ws + 9 * MB + 512 * KB + 10 * MB);  // 1 KB (precleared -1)

  k0_init<<<dim3(18), dim3(512), 0, stream>>>(
      mask, flag, W_a, W_b, w_aff, WaF, WbF, (float4*)markers);
  mega<<<dim3(256), dim3(512), 0, stream>>>(
      out_emb, pos, in_emb, pad, mask, flag, WaF, WbF, Bm_h,
      b_aff, P, partInit, partIter, markers);
}